// Round 5
// baseline (27.061 us; speedup 1.0000x reference)
//
#include <hip/hip_runtime.h>

#define NS 384
#define NT 384
#define D  256
#define NG 96                 // groups of 4
#define K2_BLOCKS 144         // dot GEMM: 24 row-tiles x 6 col-blocks (4 waves)
#define K4_BLOCKS 96          // W GEMM: 24 row-tiles x 4 col-blocks (4 waves)
#define K5_BLOCKS 96          // 4 targets per block

typedef __attribute__((ext_vector_type(8))) short bf16x8;
typedef __attribute__((ext_vector_type(4))) float f32x4;

__device__ __forceinline__ float wave_sum64(float v) {
#pragma unroll
    for (int off = 32; off; off >>= 1) v += __shfl_xor(v, off, 64);
    return v;
}
__device__ __forceinline__ unsigned short f2bf(float f) {   // RNE f32 -> bf16 bits
    unsigned u = __float_as_uint(f);
    return (unsigned short)((u + 0x7FFFu + ((u >> 16) & 1u)) >> 16);
}
__device__ __forceinline__ float bf2f(unsigned short h) {
    return __uint_as_float(((unsigned)h) << 16);
}

// K1: bf16 casts (+ src transposed copy), row norms (f32 exact), 4x4
// block-diagonal Gram of src (f32 exact), accumulator reset.
__global__ __launch_bounds__(256) void k_pre(
        const float* __restrict__ src, const float* __restrict__ trgt,
        unsigned short* __restrict__ src_bf, unsigned short* __restrict__ trgt_bf,
        unsigned short* __restrict__ srcT, float* __restrict__ ns2,
        float* __restrict__ nt2, float* __restrict__ Gblk,
        unsigned long long* __restrict__ llsum, unsigned* __restrict__ cnt) {
    const int b = blockIdx.x, tid = threadIdx.x;
    const int wave = tid >> 6, lane = tid & 63;
    if (b == 0 && tid == 0) { *llsum = 0ull; *cnt = 0u; }

    const float sv = src[b * D + tid];
    src_bf[b * D + tid] = f2bf(sv);
    srcT[tid * NS + b]  = f2bf(sv);          // [d][i] layout for W-GEMM B-frags
    const float tv = trgt[b * D + tid];
    trgt_bf[b * D + tid] = f2bf(tv);

    __shared__ float red[2][4];
    const float a = wave_sum64(sv * sv);
    const float c = wave_sum64(tv * tv);
    if (lane == 0) { red[0][wave] = a; red[1][wave] = c; }
    __syncthreads();
    if (tid == 0) ns2[b] = red[0][0] + red[0][1] + red[0][2] + red[0][3];
    if (tid == 1) nt2[b] = red[1][0] + red[1][1] + red[1][2] + red[1][3];

    if ((b & 3) == 0) {                       // block-diag Gram for group g
        const int g = b >> 2;
#pragma unroll
        for (int q = 0; q < 4; ++q) {
            const int p  = wave * 4 + q;      // pair index 0..15
            const int ra = 4 * g + (p >> 2), rb = 4 * g + (p & 3);
            const float4 va = ((const float4*)(src + ra * D))[lane];
            const float4 vb = ((const float4*)(src + rb * D))[lane];
            float d = va.x * vb.x + va.y * vb.y + va.z * vb.z + va.w * vb.w;
            d = wave_sum64(d);
            if (lane == 0) Gblk[g * 16 + p] = d;
        }
    }
}

// K2: dot[t][i] = trgt . src (bf16 MFMA, f32 acc) + fused rn epilogue.
// Wave computes one 16x16 tile over K=256 (8 MFMA). gemm_bt pattern:
// A-frag/B-frag = 16B contiguous from row-major [M][K] / [N][K].
__global__ __launch_bounds__(256) void k_dot(
        const unsigned short* __restrict__ trgt_bf,
        const unsigned short* __restrict__ src_bf,
        const float* __restrict__ nt2, const float* __restrict__ ns2,
        float* __restrict__ dot, unsigned short* __restrict__ rnb) {
    const int b = blockIdx.x;
    const int w = threadIdx.x >> 6, l = threadIdx.x & 63;
    const int t0 = (b / 6) * 16;
    const int i0 = ((b % 6) * 4 + w) * 16;
    const int lr = l & 15, lk = (l >> 4) * 8;

    f32x4 acc = {0.f, 0.f, 0.f, 0.f};
#pragma unroll
    for (int kk = 0; kk < 8; ++kk) {
        const bf16x8 af = *(const bf16x8*)(trgt_bf + (t0 + lr) * D + kk * 32 + lk);
        const bf16x8 bf = *(const bf16x8*)(src_bf  + (i0 + lr) * D + kk * 32 + lk);
        acc = __builtin_amdgcn_mfma_f32_16x16x32_bf16(af, bf, acc, 0, 0, 0);
    }
    const int col = i0 + lr;
    const float nsv = ns2[col];
#pragma unroll
    for (int r = 0; r < 4; ++r) {
        const int row = t0 + (l >> 4) * 4 + r;     // D: col=lane&15, row=(lane>>4)*4+r
        const float d  = acc[r];
        const float n2 = nt2[row] + nsv - 2.f * d; // norms ~22, EPS never binds
        const float rn = rsqrtf(n2);
        dot[row * NS + col] = d;
        rnb[row * NS + col] = f2bf(rn);
    }
}

// K3: per-t row scan. A_t = sum_i bf16(rn)  (consistent with W-GEMM operand);
// grp_t = sum_g [ ||t||^2 R^2 - 2 R P + sum_{ab} rn_a rn_b G_ab ].
__global__ __launch_bounds__(128) void k_rows(
        const float* __restrict__ dot, const unsigned short* __restrict__ rnb,
        const float* __restrict__ nt2, const float* __restrict__ Gblk,
        float* __restrict__ At, float* __restrict__ grp) {
    const int t = blockIdx.x, tid = threadIdx.x;
    const int wave = tid >> 6, lane = tid & 63;
    float quad = 0.f, asum = 0.f;
    if (tid < NG) {
        const int g = tid;
        const ushort4 rb = *(const ushort4*)(rnb + t * NS + 4 * g);
        const float4  dv = *(const float4*)(dot + t * NS + 4 * g);
        const float r0 = bf2f(rb.x), r1 = bf2f(rb.y), r2 = bf2f(rb.z), r3 = bf2f(rb.w);
        asum = r0 + r1 + r2 + r3;
        const float R = asum;
        const float P = r0 * dv.x + r1 * dv.y + r2 * dv.z + r3 * dv.w;
        const float* Gg = Gblk + g * 16;
        const float rr[4] = {r0, r1, r2, r3};
        float q2 = 0.f;
#pragma unroll
        for (int a = 0; a < 4; ++a)
#pragma unroll
            for (int c = 0; c < 4; ++c) q2 += rr[a] * rr[c] * Gg[a * 4 + c];
        quad = nt2[t] * R * R - 2.f * R * P + q2;
    }
    const float qw = wave_sum64(quad), aw = wave_sum64(asum);
    __shared__ float s[2][2];
    if (lane == 0) { s[0][wave] = qw; s[1][wave] = aw; }
    __syncthreads();
    if (tid == 0) { grp[t] = s[0][0] + s[0][1]; At[t] = s[1][0] + s[1][1]; }
}

// K4: W[t][d] = sum_i rn[t,i] * src[i][d]  (bf16 MFMA, K=384 -> 12 steps).
// B comes from srcT[d][i] so both frags are contiguous 16B row loads.
__global__ __launch_bounds__(256) void k_w(
        const unsigned short* __restrict__ rnb,
        const unsigned short* __restrict__ srcT, float* __restrict__ W) {
    const int b = blockIdx.x;
    const int w = threadIdx.x >> 6, l = threadIdx.x & 63;
    const int t0 = (b / 4) * 16;
    const int d0 = ((b % 4) * 4 + w) * 16;
    const int lr = l & 15, lk = (l >> 4) * 8;

    f32x4 acc = {0.f, 0.f, 0.f, 0.f};
#pragma unroll
    for (int kk = 0; kk < 12; ++kk) {
        const bf16x8 af = *(const bf16x8*)(rnb  + (t0 + lr) * NS + kk * 32 + lk);
        const bf16x8 bf = *(const bf16x8*)(srcT + (d0 + lr) * NS + kk * 32 + lk);
        acc = __builtin_amdgcn_mfma_f32_16x16x32_bf16(af, bf, acc, 0, 0, 0);
    }
#pragma unroll
    for (int r = 0; r < 4; ++r)
        W[(t0 + (l >> 4) * 4 + r) * D + (d0 + lr)] = acc[r];
}

// K5: loss_t = ||A_t * t - W_t||^2 - 2*grp_t; deterministic fixed-point
// global sum (proven R4); last-arriving block writes the scalar.
__global__ __launch_bounds__(256) void k_final(
        const float* __restrict__ trgt, const float* __restrict__ W,
        const float* __restrict__ At, const float* __restrict__ grp,
        unsigned long long* __restrict__ llsum, unsigned* __restrict__ cnt,
        float* __restrict__ out) {
    const int tid = threadIdx.x, wave = tid >> 6, lane = tid & 63;
    __shared__ float sR[4][4];
#pragma unroll
    for (int tt = 0; tt < 4; ++tt) {
        const int t = blockIdx.x * 4 + tt;
        const float Sd = At[t] * trgt[t * D + tid] - W[t * D + tid];
        const float v = wave_sum64(Sd * Sd);
        if (lane == 0) sR[tt][wave] = v;
    }
    __syncthreads();
    if (tid == 0) {
        double tot = 0.0;
#pragma unroll
        for (int tt = 0; tt < 4; ++tt) {
            const int t = blockIdx.x * 4 + tt;
            const float ls = sR[tt][0] + sR[tt][1] + sR[tt][2] + sR[tt][3];
            tot += (double)(ls - 2.f * grp[t]);
        }
        const long long ll = llrint(tot * 1048576.0);   // 2^20 fixed point
        atomicAdd(llsum, (unsigned long long)ll);
        __threadfence();
        const unsigned old = atomicAdd(cnt, 1u);
        if (old == K5_BLOCKS - 1) {
            const unsigned long long sv = atomicAdd(llsum, 0ull);
            const double total = (double)(long long)sv / 1048576.0;
            out[0] = (float)(total / ((double)NS * (double)NS * (double)NT));
        }
    }
}

extern "C" void kernel_launch(void* const* d_in, const int* in_sizes, int n_in,
                              void* d_out, int out_size, void* d_ws, size_t ws_size,
                              hipStream_t stream) {
    const float* src  = (const float*)d_in[0];   // [384,256] f32
    const float* trgt = (const float*)d_in[1];   // [384,256] f32

    float* dot  = (float*)d_ws;                  // [NT][NS]
    float* W    = dot + (size_t)NT * NS;         // [NT][D]
    float* ns2  = W + (size_t)NT * D;            // [NS]
    float* nt2  = ns2 + NS;                      // [NT]
    float* Gblk = nt2 + NT;                      // [NG][16]
    float* At   = Gblk + NG * 16;                // [NT]
    float* grp  = At + NT;                       // [NT]
    unsigned long long* llsum = (unsigned long long*)(grp + NT);  // 8B aligned
    unsigned* cnt = (unsigned*)(llsum + 1);
    unsigned short* src_bf  = (unsigned short*)(llsum + 2);       // 16B aligned
    unsigned short* trgt_bf = src_bf + (size_t)NS * D;
    unsigned short* srcT    = trgt_bf + (size_t)NT * D;           // [D][NS]
    unsigned short* rnb     = srcT + (size_t)D * NS;              // [NT][NS]
    float* out = (float*)d_out;

    k_pre  <<<NS,        256, 0, stream>>>(src, trgt, src_bf, trgt_bf, srcT,
                                           ns2, nt2, Gblk, llsum, cnt);
    k_dot  <<<K2_BLOCKS, 256, 0, stream>>>(trgt_bf, src_bf, nt2, ns2, dot, rnb);
    k_rows <<<NT,        128, 0, stream>>>(dot, rnb, nt2, Gblk, At, grp);
    k_w    <<<K4_BLOCKS, 256, 0, stream>>>(rnb, srcT, W);
    k_final<<<K5_BLOCKS, 256, 0, stream>>>(trgt, W, At, grp, llsum, cnt, out);
}